// Round 9
// baseline (113.790 us; speedup 1.0000x reference)
//
#include <hip/hip_runtime.h>

typedef unsigned long long u64;
typedef unsigned short u16;
typedef unsigned u32;
typedef unsigned char u8;

#define PRE   2000
#define POST  300
#define NCLS  5
#define CAP   512
#define INF   0x7fffffff
#define MAGIC 0x13579BDFu
#define NBLK  81
#define SORTB 80

// Exact threshold midpoint: fl32(inter/uni) > 0.55f  <=>  inter >= MID*uni (uni>0).
// MID = 0.55f + 2^-25; MID*(24-bit uni) exact in f64 -> bit-exact predicate.
// Validated: absmax == 0.0 in prior rounds.
#define MID 0x1.19999A8p-1

template <int K> struct IC { static constexpr int v = K; };
template <int N, typename F> __device__ __forceinline__ void unrollN(F&& f) {
    if constexpr (N > 0) { unrollN<N - 1>(f); f(IC<N - 1>{}); }
}

__device__ __forceinline__ u32 aload_acq(u32* p) {
    return __hip_atomic_load(p, __ATOMIC_ACQUIRE, __HIP_MEMORY_SCOPE_AGENT);
}

__device__ __forceinline__ float rlF(float v, int l) {
    return __uint_as_float((u32)__builtin_amdgcn_readlane((int)__float_as_uint(v), l));
}

__device__ __forceinline__ bool iou_pred(float bx0, float bx1, float bx2, float bx3,
                                         float a1, float m0, float m1, float m2, float m3,
                                         float a2) {
    const float ltx = fmaxf(bx0, m0), lty = fmaxf(bx1, m1);
    const float rbx = fminf(bx2, m2), rby = fminf(bx3, m3);
    const float wd = fmaxf(rbx - ltx, 0.f), hg = fmaxf(rby - lty, 0.f);
    const float inter = wd * hg;
    const float uni = (a1 + a2) - inter;
    return (uni > 0.f) && ((double)inter >= MID * (double)uni);
}

// Sort key: stored = ~(score_bits<<32 | (0xFFFF-g)<<16 | id). Ascending stored
// == descending (score, -g, id). Bucket = stored>>52; real <= 0xC2B, pad 0xFFF.
__device__ __forceinline__ u64 mk_key(float sc, int g, int id) {
    return ~(((u64)__float_as_uint(sc) << 32) |
             ((u64)(unsigned)(0xFFFF - g) << 16) | (u64)id);
}

// Fused: blocks 0..79 = matrix (cls=b>>4, 4-row slices/wave); block (b&15)==0
// continues as its class's scan block; block 80 sorts. Handshake via ctrl.
__global__ __launch_bounds__(512, 1) void wbf_all(const float* __restrict__ x,
                                                  u64* __restrict__ M,
                                                  float* __restrict__ recs,
                                                  int* __restrict__ cnts,
                                                  u64* __restrict__ keysg,
                                                  u32* __restrict__ histg,
                                                  u32* __restrict__ ctrl,
                                                  float* __restrict__ out) {
#pragma clang fp contract(off)
    __shared__ __align__(16) char s_buf[58464];
    u8*  s_mtx = (u8*)s_buf;                                 // 32768
    float (*s_det)[8]  = (float (*)[8])(s_buf + 32768);      // 16384
    float (*s_dov)[16] = (float (*)[16])(s_buf + 49152);     // 8192: overflow dirty
    u8*  s_ab          = (u8*)(s_buf + 57344);               // 64: shared alive bytes
    u16* s_list        = (u16*)(s_buf + 57408);              // 1024
    int* s_wc          = (int*)(s_buf + 58432);              // 32

    const int tid  = threadIdx.x;
    const int lane = tid & 63;
    const int wave = tid >> 6;
    const int b    = blockIdx.x;

    // ================= SORT BLOCK =================
    if (b == SORTB) {
        u64* keysL  = (u64*)s_buf;             // 20480 (fallback path only)
        u64* cand   = (u64*)(s_buf + 20480);   // 4096
        u64* sorted = (u64*)(s_buf + 24576);   // 4096
        u32* part   = (u32*)(s_buf + 28672);   // 32
        int* scal   = (int*)(s_buf + 28704);

        if (tid == 0) { while (aload_acq(&ctrl[32]) != MAGIC) {} }
        __syncthreads();
        if (tid == 0) { while (aload_acq(&ctrl[16]) < (u32)NCLS) {} }
        __syncthreads();
        if (tid == 0) { scal[0] = 0; scal[1] = 0; scal[2] = 0; }

        int n = 0;
        #pragma unroll
        for (int w = 0; w < NCLS; ++w) n += cnts[w];
        const int target = (POST < n) ? POST : n;

        // prefix over 4096 bins: 8/thread + shfl scan (1 barrier)
        u32 p = 0;
        #pragma unroll
        for (int k = 0; k < 8; ++k) p += histg[tid * 8 + k];
        u32 v = p;
        #pragma unroll
        for (int o2 = 1; o2 < 64; o2 <<= 1) {
            const u32 t = (u32)__shfl_up((int)v, o2);
            if (lane >= o2) v += t;
        }
        if (lane == 63) part[wave] = v;
        __syncthreads();
        u32 base = 0;
        #pragma unroll
        for (int w = 0; w < 8; ++w) base += (w < wave) ? part[w] : 0u;
        const u32 I = base + v;
        const u32 E = I - p;
        if ((int)E < target && (int)I >= target) { scal[0] = tid; scal[1] = (int)E; }
        __syncthreads();
        const int T = scal[0];
        int cum = scal[1];
        int B = T * 8 + 7;
        for (int bb = T * 8; bb < T * 8 + 8; ++bb) {
            const int h = (int)histg[bb];
            if (cum + h >= target) { B = bb; break; }
            cum += h;
        }
        const int candCount = cum + (int)histg[B];

        if (candCount <= 512) {
            // wave-ballot compaction over 2560 fixed slots (pads self-exclude)
            #pragma unroll
            for (int b2 = 0; b2 < NCLS * CAP; b2 += 512) {
                const u64 kk = keysg[b2 + tid];
                const bool pred = ((u32)(kk >> 52) <= (u32)B);
                const u64 m = __ballot(pred);
                if (m) {
                    int wbase = 0;
                    if (lane == 0) wbase = atomicAdd(&scal[2], (int)__popcll(m));
                    wbase = __builtin_amdgcn_readfirstlane(wbase);
                    if (pred) {
                        const int pos = wbase + (int)__popcll(m & (((u64)1 << lane) - 1ull));
                        cand[pos] = kk;
                    }
                }
            }
            __syncthreads();
            // unique pads, strictly greater than every real key
            if (tid >= candCount) cand[tid] = (~0ull << 16) | (u64)(0xF000u + tid);
            __syncthreads();
            // LDS-broadcast rank-count (keys unique: strict <)
            const u64 myk = cand[tid];
            int rk = 0;
            #pragma unroll 4
            for (int j = 0; j < 512; ++j) {
                const u64 kj = cand[j];
                rk += (int)(kj < myk);
            }
            sorted[rk] = myk;   // pad ranks >= candCount >= target: never read
            __syncthreads();
        } else {
            // fallback (~never): full rank over all 2560 slots, 5 per thread
            for (int i = tid; i < NCLS * CAP; i += 512) keysL[i] = keysg[i];
            __syncthreads();
            u64 myk5[5]; int rk5[5];
            #pragma unroll
            for (int s = 0; s < 5; ++s) { myk5[s] = keysL[s * 512 + tid]; rk5[s] = 0; }
            for (int j = 0; j < NCLS * CAP; ++j) {
                const u64 kj = keysL[j];
                #pragma unroll
                for (int s = 0; s < 5; ++s)
                    rk5[s] += (int)((kj < myk5[s]) || (kj == myk5[s] && j < s * 512 + tid));
            }
            #pragma unroll
            for (int s = 0; s < 5; ++s)
                if (rk5[s] < 512) sorted[rk5[s]] = myk5[s];
            __syncthreads();
        }

        if (tid < POST) {
            float* o = out + tid * 6;
            if (tid < target) {
                const u64 key = ~sorted[tid];
                const int id = (int)(key & 0xFFFFull);
                const float* rec = recs + (size_t)id * 8;
                o[0] = rec[0]; o[1] = rec[1]; o[2] = rec[2]; o[3] = rec[3];
                o[4] = __uint_as_float((unsigned)(key >> 32));
                o[5] = (float)(id >> 9);
            } else {
                o[0] = 0.f; o[1] = 0.f; o[2] = 0.f; o[3] = 0.f; o[4] = 0.f; o[5] = 0.f;
            }
        }
        return;
    }

    // ================= MATRIX BLOCKS (0..79) =================
    const int cls = b >> 4;
    const float mycls = (float)cls;

    // ---- init handshake (ws re-poisoned 0xAA before every launch) ----
    if (b == 0) {
        for (int i = tid; i < NCLS * CAP; i += 512) keysg[i] = ~0ull;
        for (int i = tid; i < 4096; i += 512) histg[i] = 0u;
        if (tid == 0) {
            for (int i = 0; i < NCLS; ++i)
                __hip_atomic_store(&ctrl[i], 0u, __ATOMIC_RELAXED, __HIP_MEMORY_SCOPE_AGENT);
            __hip_atomic_store(&ctrl[16], 0u, __ATOMIC_RELAXED, __HIP_MEMORY_SCOPE_AGENT);
        }
        __syncthreads();
        if (tid == 0) {
            __threadfence();
            __hip_atomic_store(&ctrl[32], MAGIC, __ATOMIC_RELEASE, __HIP_MEMORY_SCOPE_AGENT);
        }
    } else {
        if (tid == 0) { while (aload_acq(&ctrl[32]) != MAGIC) {} }
    }
    __syncthreads();

    // ---- parallel class-list build: 8 waves, 4 ballot-iters each ----
    u64 wm[4]; int wcnt = 0;
    const int tb = wave * 256;
    #pragma unroll
    for (int i = 0; i < 4; ++i) {
        const int t = tb + i * 64 + lane;
        const bool pp = (t < PRE) && (x[t * 6 + 5] == mycls);
        wm[i] = __ballot(pp);
        wcnt += (int)__popcll(wm[i]);
    }
    if (lane == 0) s_wc[wave] = wcnt;
    __syncthreads();
    int off = 0, tot = 0;
    #pragma unroll
    for (int w = 0; w < 8; ++w) {
        const int cw = s_wc[w];
        off += (w < wave) ? cw : 0;
        tot += cw;
    }
    #pragma unroll
    for (int i = 0; i < 4; ++i) {
        const int t = tb + i * 64 + lane;
        const bool pp = ((wm[i] >> lane) & 1ull) != 0ull;
        const int pos = off + (int)__popcll(wm[i] & (((u64)1 << lane) - 1ull));
        if (pp && pos < CAP) s_list[pos] = (u16)t;
        off += (int)__popcll(wm[i]);
    }
    const int myn = (tot > CAP) ? CAP : tot;
    __syncthreads();   // s_list ready

    {
        float qc0[8], qc1[8], qc2[8], qc3[8], ac[8];
        unrollN<8>([&](auto k_) {
            constexpr int K = decltype(k_)::v;
            const int c = K * 64 + lane;
            qc0[K] = 0.f; qc1[K] = 0.f; qc2[K] = 0.f; qc3[K] = 0.f; ac[K] = 0.f;
            if (c < myn) {
                const int g = s_list[c];
                const float* p = x + g * 6;
                const float b0 = p[0], b1 = p[1], b2 = p[2], b3 = p[3], sc = p[4];
                qc0[K] = (sc * b0) / sc; qc1[K] = (sc * b1) / sc;
                qc2[K] = (sc * b2) / sc; qc3[K] = (sc * b3) / sc;
                ac[K] = (qc2[K] - qc0[K]) * (qc3[K] - qc1[K]);
            }
        });
        const int slice = (b & 15) * 8 + wave;   // 128 slices x 4 rows = 512
        const int rlo = slice * 4;
        const int rhi = (rlo + 4 < myn) ? rlo + 4 : myn;
        const int nr = rhi - rlo;
        if (nr > 0) {
            float rv0 = 0.f, rv1 = 0.f, rv2 = 0.f, rv3 = 0.f;
            if (lane < nr) {
                const int g = s_list[rlo + lane];
                const float* p = x + g * 6;
                rv0 = p[0]; rv1 = p[1]; rv2 = p[2]; rv3 = p[3];
            }
            for (int i = 0; i < nr; ++i) {
                const int r = rlo + i;
                const float bx0 = rlF(rv0, i), bx1 = rlF(rv1, i);
                const float bx2 = rlF(rv2, i), bx3 = rlF(rv3, i);
                const float a1 = (bx2 - bx0) * (bx3 - bx1);
                const int Wmax = r >> 6;   // words > Wmax have no bits c<r
                unrollN<8>([&](auto w_) {
                    constexpr int W = decltype(w_)::v;
                    if (W <= Wmax) {
                        const int c = W * 64 + lane;
                        const bool pred = (c < r) &&
                            iou_pred(bx0, bx1, bx2, bx3, a1, qc0[W], qc1[W], qc2[W], qc3[W], ac[W]);
                        const u64 bits = __ballot(pred);
                        if (lane == 0) M[((size_t)(cls * CAP + r)) * 8 + W] = bits;
                    }
                });
            }
        }
    }
    // per-wave completion (wave-level vmcnt fence covers the wave's stores)
    __threadfence();
    if (lane == 0)
        __hip_atomic_fetch_add(&ctrl[cls], 1u, __ATOMIC_RELEASE, __HIP_MEMORY_SCOPE_AGENT);

    if ((b & 15) != 0) return;

    // ================= SCAN BLOCK (one per class) =================
    // fill s_det locally from x (no global round-trip) while matrix completes
    for (int rr = tid; rr < myn; rr += 512) {
        const int g = s_list[rr];
        const float* p = x + g * 6;
        const float b0 = p[0], b1 = p[1], b2 = p[2], b3 = p[3], sc = p[4];
        s_det[rr][0] = b0; s_det[rr][1] = b1; s_det[rr][2] = b2; s_det[rr][3] = b3;
        s_det[rr][4] = sc; s_det[rr][5] = (b2 - b0) * (b3 - b1);
        ((int*)s_det[rr])[6] = g;
    }
    if (tid < 64) s_ab[tid] = 0;
    if (tid == 0) { while (aload_acq(&ctrl[cls]) < 128u) {} }   // 16 blocks x 8 waves
    __syncthreads();
    {   // stage matrix rows (myn*64B) with 512 threads
        const ulonglong2* Mg = (const ulonglong2*)(M + (size_t)cls * CAP * 8);
        ulonglong2* Ml = (ulonglong2*)s_mtx;
        const int nit = myn * 4;
        for (int it = tid; it < nit; it += 512) Ml[it] = Mg[it];
    }
    __syncthreads();
    if (wave != 0) return;

    // ================= SCAN (wave 0) =================
    u32 aliveB = 0;
    int dirtyCnt = 0;
    bool consA = false;
    int resCode = 0, resIdx = 0;
    float dR0 = 0.f, dR1 = 0.f, dR2 = 0.f, dR3 = 0.f, dRa = 0.f;
    float dS0 = 0.f, dS1 = 0.f, dS2 = 0.f, dS3 = 0.f, dSs = 0.f;
    int dRank = INF, dGi = 0, dCnt = 0;
    float rm0 = 0.f, rm1 = 0.f, rm2 = 0.f, rm3 = 0.f, rma = 0.f;

    auto resolve = [&](int r, float bx0, float bx1, float bx2, float bx3,
                       float sc, float a1, u32 rowByte, u64 balC) {
        const u32 mC = rowByte & aliveB;
        int rank_c = INF;
        if (balC) {
            const int wl = (int)__builtin_ctzll(balC);
            const u32 byte = (u32)__builtin_amdgcn_readlane((int)mC, wl);
            rank_c = wl * 8 + (int)__builtin_ctz(byte);
        }
        const int rcs = (rank_c == INF) ? 0 : rank_c;
        const float4 cbv = *(const float4*)&s_det[rcs][0];
        const float4 cbe = *(const float4*)&s_det[rcs][4];
        const float cb0 = cbv.x, cb1 = cbv.y, cb2 = cbv.z, cb3 = cbv.w;
        const float csc = cbe.x;
        const int cgi = __float_as_int(cbe.z);

        int rank_d = INF, di = -1;
        if (dirtyCnt > 0) {
            const int DN = (dirtyCnt < 64) ? dirtyCnt : 64;
            const bool p = (lane < DN) &&
                iou_pred(bx0, bx1, bx2, bx3, a1, dR0, dR1, dR2, dR3, dRa);
            const int myrk = p ? dRank : INF;
            u64 mk = __ballot(p);
            while (mk) {
                const int l = (int)__builtin_ctzll(mk);
                mk &= mk - 1;
                const int rk = __builtin_amdgcn_readlane(myrk, l);
                if (rk < rank_d) { rank_d = rk; di = l; }
            }
            const int DH2 = (dirtyCnt < 128) ? dirtyCnt : 128;
            for (int dd = 64; dd < DH2; ++dd) {
                const float* dv = s_dov[dd];
                if (iou_pred(bx0, bx1, bx2, bx3, a1, dv[0], dv[1], dv[2], dv[3], dv[4])) {
                    const int rk = ((const int*)dv)[10];
                    if (rk < rank_d) { rank_d = rk; di = dd; }
                }
            }
        }
        if (rank_c == INF && rank_d == INF) {
            aliveB |= ((r >> 3) == lane) ? (1u << (r & 7)) : 0u;
            resCode = 0;
        } else if (rank_c < rank_d) {
            const int rc = rank_c;
            aliveB &= ~(((rc >> 3) == lane) ? (1u << (rc & 7)) : 0u);
            const float ns0 = (csc * cb0) + sc * bx0;
            const float ns1 = (csc * cb1) + sc * bx1;
            const float ns2 = (csc * cb2) + sc * bx2;
            const float ns3 = (csc * cb3) + sc * bx3;
            const float nss = csc + sc;
            const float nm0 = ns0 / nss, nm1 = ns1 / nss;
            const float nm2 = ns2 / nss, nm3 = ns3 / nss;
            const float nar = (nm2 - nm0) * (nm3 - nm1);
            const int D = dirtyCnt;
            if (D < 64) {
                if (lane == D) {
                    dR0 = nm0; dR1 = nm1; dR2 = nm2; dR3 = nm3; dRa = nar;
                    dS0 = ns0; dS1 = ns1; dS2 = ns2; dS3 = ns3; dSs = nss;
                    dRank = rc; dGi = cgi; dCnt = 2;
                }
            } else if (D < 128) {
                if (lane == 0) {
                    float* dv = s_dov[D];
                    dv[0] = nm0; dv[1] = nm1; dv[2] = nm2; dv[3] = nm3; dv[4] = nar;
                    dv[5] = ns0; dv[6] = ns1; dv[7] = ns2; dv[8] = ns3; dv[9] = nss;
                    ((int*)dv)[10] = rc; ((int*)dv)[11] = cgi; ((int*)dv)[12] = 2;
                }
            }
            dirtyCnt++;
            resCode = 1; resIdx = D;
            rm0 = nm0; rm1 = nm1; rm2 = nm2; rm3 = nm3; rma = nar;
        } else {
            float f0, f1, f2, f3, fs; int nct;
            if (di < 64) {
                f0 = rlF(dS0, di) + sc * bx0; f1 = rlF(dS1, di) + sc * bx1;
                f2 = rlF(dS2, di) + sc * bx2; f3 = rlF(dS3, di) + sc * bx3;
                fs = rlF(dSs, di) + sc;
                nct = __builtin_amdgcn_readlane(dCnt, di) + 1;
            } else {
                const float* dv = s_dov[di];
                f0 = dv[5] + sc * bx0; f1 = dv[6] + sc * bx1;
                f2 = dv[7] + sc * bx2; f3 = dv[8] + sc * bx3;
                fs = dv[9] + sc;
                nct = ((const int*)dv)[12] + 1;
            }
            const float nm0 = f0 / fs, nm1 = f1 / fs, nm2 = f2 / fs, nm3 = f3 / fs;
            const float nar = (nm2 - nm0) * (nm3 - nm1);
            if (di < 64) {
                if (lane == di) {
                    dR0 = nm0; dR1 = nm1; dR2 = nm2; dR3 = nm3; dRa = nar;
                    dS0 = f0; dS1 = f1; dS2 = f2; dS3 = f3; dSs = fs; dCnt = nct;
                }
            } else {
                if (lane == 0) {
                    float* dw = s_dov[di];
                    dw[0] = nm0; dw[1] = nm1; dw[2] = nm2; dw[3] = nm3; dw[4] = nar;
                    dw[5] = f0; dw[6] = f1; dw[7] = f2; dw[8] = f3; dw[9] = fs;
                    ((int*)dw)[12] = nct;
                }
            }
            rm0 = nm0; rm1 = nm1; rm2 = nm2; rm3 = nm3; rma = nar;
            resCode = 2; resIdx = di;
        }
    };

    // ---- batched scan: 64-det chunks ----
    unrollN<8>([&](auto k_) {
        constexpr int K = decltype(k_)::v;
        const int r0 = K * 64;
        if (r0 < myn) {
            const int cnt = (myn - r0 < 64) ? (myn - r0) : 64;
            const bool valid = lane < cnt;
            const u64 validM = (cnt == 64) ? ~0ull : (((u64)1 << cnt) - 1ull);
            u64 orv = 0ull;
            {
                const int rr = r0 + (valid ? lane : 0);
                const u64* rp = (const u64*)&s_mtx[(size_t)rr * 64];
                const u64* av = (const u64*)s_ab;
                unrollN<8>([&](auto w_) {
                    constexpr int W = decltype(w_)::v;
                    if (W < K)       orv |= rp[W] & av[W];
                    else if (W == K) orv |= rp[W];
                });
            }
            const u64 rowW = __ballot(valid && orv != 0ull);
            float4 db = make_float4(0.f, 0.f, 0.f, 0.f);
            float2 de = make_float2(1.f, 0.f);
            if (valid) {
                db = *(const float4*)&s_det[r0 + lane][0];
                de = *(const float2*)&s_det[r0 + lane][4];
            }
            u64 dmaskLo = 0ull, dmaskHi = 0ull;
            if (!consA) {
                const int DN = (dirtyCnt < 64) ? dirtyCnt : 64;
                for (int d = 0; d < DN; ++d) {
                    const float m0 = rlF(dR0, d), m1 = rlF(dR1, d);
                    const float m2 = rlF(dR2, d), m3 = rlF(dR3, d);
                    const float ma = rlF(dRa, d);
                    const bool pp = valid && iou_pred(db.x, db.y, db.z, db.w, de.y,
                                                     m0, m1, m2, m3, ma);
                    if (pp) dmaskLo |= 1ull << d;
                }
                const int DH = (dirtyCnt < 128) ? dirtyCnt : 128;
                for (int dd = 64; dd < DH; ++dd) {
                    const float* dv = s_dov[dd];
                    const bool pp = valid && iou_pred(db.x, db.y, db.z, db.w, de.y,
                                                     dv[0], dv[1], dv[2], dv[3], dv[4]);
                    if (pp) dmaskHi |= 1ull << (dd - 64);
                }
            }
            u64 danyb = __ballot((dmaskLo | dmaskHi) != 0ull);

            // prefetch row bytes for the first 8 candidate violations
            u32 prB[8]; int prP[8];
            {
                u64 t = consA ? validM : ((danyb | rowW) & validM);
                #pragma unroll
                for (int i = 0; i < 8; ++i) {
                    const int f = t ? (int)__builtin_ctzll(t) : 0;
                    prP[i] = t ? f : 64;
                    prB[i] = (u32)s_mtx[(size_t)(r0 + f) * 64 + lane];
                    t &= t - 1ull;
                }
            }

            int p = 0;
            while (p < cnt) {
                u64 vm = consA ? validM : ((danyb | rowW) & validM);
                vm &= ~(((u64)1 << p) - 1ull);
                const int F = vm ? (int)__builtin_ctzll(vm) : cnt;
                {   // commit creates [r0+p, r0+F)
                    const int lo = r0 + p, h2 = r0 + F;
                    int s = lo - 8 * lane; s = (s > 0) ? s : 0;
                    int e = h2 - 8 * lane; e = (e < 8) ? e : 8;
                    if (e > s) aliveB |= ((0xFFu >> (8 - (e - s))) << s);
                }
                s_ab[lane] = (u8)aliveB;
                if (F >= cnt) break;
                const int r = r0 + F;
                u32 rowByte = 0u; bool hit = false;
                #pragma unroll
                for (int i = 0; i < 8; ++i)
                    if (prP[i] == F) { rowByte = prB[i]; hit = true; }
                if (!hit) rowByte = (u32)s_mtx[(size_t)r * 64 + lane];
                const u64 balCq = __ballot((rowByte & aliveB) != 0u);
                const bool Fdirty = consA || (((danyb >> F) & 1ull) != 0ull);
                if (!Fdirty && balCq == 0ull) {
                    aliveB |= ((r >> 3) == lane) ? (1u << (r & 7)) : 0u;
                    s_ab[lane] = (u8)aliveB;
                } else {
                    const float bx0 = rlF(db.x, F), bx1 = rlF(db.y, F);
                    const float bx2 = rlF(db.z, F), bx3 = rlF(db.w, F);
                    const float sc = rlF(de.x, F), a1 = rlF(de.y, F);
                    resolve(r, bx0, bx1, bx2, bx3, sc, a1, rowByte, balCq);
                    s_ab[lane] = (u8)aliveB;
                    if (resCode != 0) {
                        const int idx = resIdx;
                        if (idx < 128) {
                            const bool pnew = valid && (lane > F) &&
                                iou_pred(db.x, db.y, db.z, db.w, de.y,
                                         rm0, rm1, rm2, rm3, rma);
                            const u64 nb = __ballot(pnew);
                            const u64 bit = (nb >> lane) & 1ull;
                            if (idx < 64)
                                dmaskLo = (dmaskLo & ~(1ull << idx)) | (bit << idx);
                            else
                                dmaskHi = (dmaskHi & ~(1ull << (idx - 64))) | (bit << (idx - 64));
                            danyb = __ballot((dmaskLo | dmaskHi) != 0ull);
                        } else {
                            consA = true;
                        }
                    }
                }
                p = F + 1;
            }
        }
    });

    // ---- emit compacted records + sort keys + global histogram ----
    int wo = 0;
    for (int Kw = 0; Kw < 8; ++Kw) {
        u64 am = 0ull;
        #pragma unroll
        for (int bb = 0; bb < 8; ++bb)
            am |= (u64)(u32)(u8)__builtin_amdgcn_readlane((int)aliveB, Kw * 8 + bb) << (8 * bb);
        const int j = Kw * 64 + lane;
        const bool pred = (am >> lane) & 1ull;
        if (pred) {
            const int pos = wo + (int)__popcll(am & (((u64)1 << lane) - 1));
            const float b0 = s_det[j][0], b1 = s_det[j][1];
            const float b2 = s_det[j][2], b3 = s_det[j][3];
            const float sc = s_det[j][4];
            const int g = ((const int*)s_det[j])[6];
            const int id = cls * CAP + pos;
            float* rec = recs + (size_t)id * 8;
            rec[0] = (sc * b0) / sc; rec[1] = (sc * b1) / sc;
            rec[2] = (sc * b2) / sc; rec[3] = (sc * b3) / sc;
            rec[4] = sc;
            ((int*)rec)[5] = g;
            const u64 skey = mk_key(sc, g, id);
            keysg[id] = skey;
            atomicAdd(&histg[(u32)(skey >> 52)], 1u);
        }
        wo += (int)__popcll(am);
    }
    const int demit = (dirtyCnt < 128) ? dirtyCnt : 128;
    {
        const int dreg = (demit < 64) ? demit : 64;
        if (lane < dreg) {
            const int id = cls * CAP + wo + lane;
            float* rec = recs + (size_t)id * 8;
            const float scd = dSs / (float)dCnt;   // exact IEEE div
            rec[0] = dR0; rec[1] = dR1; rec[2] = dR2; rec[3] = dR3;
            rec[4] = scd;
            ((int*)rec)[5] = dGi;
            const u64 skey = mk_key(scd, dGi, id);
            keysg[id] = skey;
            atomicAdd(&histg[(u32)(skey >> 52)], 1u);
        }
        for (int d = 64 + lane; d < demit; d += 64) {
            const float* dv = s_dov[d];
            const int id = cls * CAP + wo + d;
            float* rec = recs + (size_t)id * 8;
            const float scd = dv[9] / (float)(((const int*)dv)[12]);
            const int g = ((const int*)dv)[11];
            rec[0] = dv[0]; rec[1] = dv[1]; rec[2] = dv[2]; rec[3] = dv[3];
            rec[4] = scd;
            ((int*)rec)[5] = g;
            const u64 skey = mk_key(scd, g, id);
            keysg[id] = skey;
            atomicAdd(&histg[(u32)(skey >> 52)], 1u);
        }
    }
    if (lane == 0) cnts[cls] = wo + demit;
    __threadfence();
    if (lane == 0)
        __hip_atomic_fetch_add(&ctrl[16], 1u, __ATOMIC_RELEASE, __HIP_MEMORY_SCOPE_AGENT);
}

extern "C" void kernel_launch(void* const* d_in, const int* in_sizes, int n_in,
                              void* d_out, int out_size, void* d_ws, size_t ws_size,
                              hipStream_t stream) {
    const float* x = (const float*)d_in[0];
    float* out = (float*)d_out;
    // ws layout: M 160K | recs 80K | cnts 256B | keys 20K | hist 16K | ctrl 256B
    u64*   M     = (u64*)d_ws;
    float* recs  = (float*)((char*)d_ws + 163840);
    int*   cnts  = (int*)((char*)d_ws + 245760);
    u64*   keysg = (u64*)((char*)d_ws + 246016);
    u32*   histg = (u32*)((char*)d_ws + 266496);
    u32*   ctrl  = (u32*)((char*)d_ws + 282880);
    wbf_all<<<NBLK, 512, 0, stream>>>(x, M, recs, cnts, keysg, histg, ctrl, out);
}

// Round 10
// 90.217 us; speedup vs baseline: 1.2613x; 1.2613x over previous
//
#include <hip/hip_runtime.h>

typedef unsigned long long u64;
typedef unsigned short u16;
typedef unsigned u32;
typedef unsigned char u8;

#define PRE   2000
#define POST  300
#define NCLS  5
#define CAP   512
#define INF   0x7fffffff
#define SORTG 8

// Exact threshold midpoint: fl32(inter/uni) > 0.55f  <=>  inter >= MID*uni (uni>0).
// MID = 0.55f + 2^-25; MID*(24-bit uni) exact in f64 -> bit-exact predicate.
// Validated: absmax == 0.0 in prior rounds.
#define MID 0x1.19999A8p-1

template <int K> struct IC { static constexpr int v = K; };
template <int N, typename F> __device__ __forceinline__ void unrollN(F&& f) {
    if constexpr (N > 0) { unrollN<N - 1>(f); f(IC<N - 1>{}); }
}

__device__ __forceinline__ float rlF(float v, int l) {
    return __uint_as_float((u32)__builtin_amdgcn_readlane((int)__float_as_uint(v), l));
}

__device__ __forceinline__ bool iou_pred(float bx0, float bx1, float bx2, float bx3,
                                         float a1, float m0, float m1, float m2, float m3,
                                         float a2) {
    const float ltx = fmaxf(bx0, m0), lty = fmaxf(bx1, m1);
    const float rbx = fminf(bx2, m2), rby = fminf(bx3, m3);
    const float wd = fmaxf(rbx - ltx, 0.f), hg = fmaxf(rby - lty, 0.f);
    const float inter = wd * hg;
    const float uni = (a1 + a2) - inter;
    return (uni > 0.f) && ((double)inter >= MID * (double)uni);
}

// Sort key: stored = ~(score_bits<<32 | (0xFFFF-g)<<16 | id). Ascending stored
// == descending (score, -g, id). Bucket = stored>>52; real <= 0xC2B, pad 0xFFF.
__device__ __forceinline__ u64 mk_key(float sc, int g, int id) {
    return ~(((u64)__float_as_uint(sc) << 32) |
             ((u64)(unsigned)(0xFFFF - g) << 16) | (u64)id);
}

// ================= K1: MATRIX (80 blocks; cls = b>>4, 4-row slices per wave) ==
// Blocks 1,2 additionally init the global keys/hist arrays (done before K2 runs).
__global__ __launch_bounds__(512, 1) void wbf_matrix(const float* __restrict__ x,
                                                     u64* __restrict__ M,
                                                     float* __restrict__ dets,
                                                     int* __restrict__ nlist,
                                                     u64* __restrict__ keysg,
                                                     u32* __restrict__ histg) {
#pragma clang fp contract(off)
    __shared__ int s_wc[8];
    __shared__ u16 s_list[CAP];

    const int tid  = threadIdx.x;
    const int lane = tid & 63;
    const int wave = tid >> 6;
    const int b    = blockIdx.x;
    const int cls  = b >> 4;
    const float mycls = (float)cls;

    if (b == 1) for (int i = tid; i < NCLS * CAP; i += 512) keysg[i] = ~0ull;
    if (b == 2) for (int i = tid; i < 4096; i += 512) histg[i] = 0u;

    // ---- parallel class-list build: 8 waves, 4 ballot-iters each ----
    u64 wm[4]; int wcnt = 0;
    const int tb = wave * 256;
    #pragma unroll
    for (int i = 0; i < 4; ++i) {
        const int t = tb + i * 64 + lane;
        const bool pp = (t < PRE) && (x[t * 6 + 5] == mycls);
        wm[i] = __ballot(pp);
        wcnt += (int)__popcll(wm[i]);
    }
    if (lane == 0) s_wc[wave] = wcnt;
    __syncthreads();
    int off = 0, tot = 0;
    #pragma unroll
    for (int w = 0; w < 8; ++w) {
        const int cw = s_wc[w];
        off += (w < wave) ? cw : 0;
        tot += cw;
    }
    #pragma unroll
    for (int i = 0; i < 4; ++i) {
        const int t = tb + i * 64 + lane;
        const bool pp = ((wm[i] >> lane) & 1ull) != 0ull;
        const int pos = off + (int)__popcll(wm[i] & (((u64)1 << lane) - 1ull));
        if (pp && pos < CAP) s_list[pos] = (u16)t;
        off += (int)__popcll(wm[i]);
    }
    const int myn = (tot > CAP) ? CAP : tot;
    __syncthreads();   // s_list ready

    {
        float qc0[8], qc1[8], qc2[8], qc3[8], ac[8];
        unrollN<8>([&](auto k_) {
            constexpr int K = decltype(k_)::v;
            const int c = K * 64 + lane;
            qc0[K] = 0.f; qc1[K] = 0.f; qc2[K] = 0.f; qc3[K] = 0.f; ac[K] = 0.f;
            if (c < myn) {
                const int g = s_list[c];
                const float* p = x + g * 6;
                const float b0 = p[0], b1 = p[1], b2 = p[2], b3 = p[3], sc = p[4];
                qc0[K] = (sc * b0) / sc; qc1[K] = (sc * b1) / sc;
                qc2[K] = (sc * b2) / sc; qc3[K] = (sc * b3) / sc;
                ac[K] = (qc2[K] - qc0[K]) * (qc3[K] - qc1[K]);
            }
        });
        const int slice = (b & 15) * 8 + wave;   // 128 slices x 4 rows = 512
        const int rlo = slice * 4;
        const int rhi = (rlo + 4 < myn) ? rlo + 4 : myn;
        const int nr = rhi - rlo;
        if (nr > 0) {
            // parallel row preload: lane i holds row rlo+i (raw box)
            float rv0 = 0.f, rv1 = 0.f, rv2 = 0.f, rv3 = 0.f;
            if (lane < nr) {
                const int g = s_list[rlo + lane];
                const float* p = x + g * 6;
                rv0 = p[0]; rv1 = p[1]; rv2 = p[2]; rv3 = p[3];
            }
            for (int i = 0; i < nr; ++i) {
                const int r = rlo + i;
                const float bx0 = rlF(rv0, i), bx1 = rlF(rv1, i);
                const float bx2 = rlF(rv2, i), bx3 = rlF(rv3, i);
                const float a1 = (bx2 - bx0) * (bx3 - bx1);
                const int Wmax = r >> 6;   // words > Wmax have no bits c<r
                unrollN<8>([&](auto w_) {
                    constexpr int W = decltype(w_)::v;
                    if (W <= Wmax) {
                        const int c = W * 64 + lane;
                        const bool pred = (c < r) &&
                            iou_pred(bx0, bx1, bx2, bx3, a1, qc0[W], qc1[W], qc2[W], qc3[W], ac[W]);
                        const u64 bits = __ballot(pred);
                        if (lane == 0) M[((size_t)(cls * CAP + r)) * 8 + W] = bits;
                    }
                });
            }
        }
    }

    // ---- persist det records (one block per class) ----
    if ((b & 15) == 0) {
        for (int rr = tid; rr < myn; rr += 512) {
            const int g = s_list[rr];
            const float* p = x + g * 6;
            const float b0 = p[0], b1 = p[1], b2 = p[2], b3 = p[3], sc = p[4];
            float* dr = dets + (size_t)(cls * CAP + rr) * 8;
            dr[0] = b0; dr[1] = b1; dr[2] = b2; dr[3] = b3;
            dr[4] = sc; dr[5] = (b2 - b0) * (b3 - b1);
            ((int*)dr)[6] = g; ((int*)dr)[7] = 0;
        }
        if (tid == 0) nlist[cls] = myn;
    }
}

// ================= K2: SCAN (5 blocks, one class each; wave 0 scans) ==========
// Dirty clusters: d<64 in lane-d registers; d in [64,128) in s_dov LDS.
// Emit also writes sort keys + global histogram (removes work from K3).
__global__ __launch_bounds__(512, 1) void wbf_scan(const u64* __restrict__ M,
                                                   const float* __restrict__ dets,
                                                   const int* __restrict__ nlist,
                                                   float* __restrict__ recs,
                                                   int* __restrict__ cnts,
                                                   u64* __restrict__ keysg,
                                                   u32* __restrict__ histg) {
#pragma clang fp contract(off)
    __shared__ __align__(16) char s_buf[57408];
    u8*  s_mtx = (u8*)s_buf;                                 // 32768
    float (*s_det)[8]  = (float (*)[8])(s_buf + 32768);      // 16384
    float (*s_dov)[16] = (float (*)[16])(s_buf + 49152);     // 8192: overflow dirty
    u8*  s_ab          = (u8*)(s_buf + 57344);               // 64: shared alive bytes

    const int tid  = threadIdx.x;
    const int lane = tid & 63;
    const int wave = tid >> 6;
    const int cls  = blockIdx.x;

    const int myn = nlist[cls];

    {   // stage matrix rows (myn*64B) with 512 threads
        const ulonglong2* Mg = (const ulonglong2*)(M + (size_t)cls * CAP * 8);
        ulonglong2* Ml = (ulonglong2*)s_mtx;
        const int nit = myn * 4;
        for (int it = tid; it < nit; it += 512) Ml[it] = Mg[it];
    }
    {   // stage det records (myn*32B)
        const float4* Dg = (const float4*)(dets + (size_t)cls * CAP * 8);
        float4* Dl = (float4*)s_det;
        const int nit = myn * 2;
        for (int it = tid; it < nit; it += 512) Dl[it] = Dg[it];
    }
    if (tid < 64) s_ab[tid] = 0;
    __syncthreads();
    if (wave != 0) return;

    // ================= SCAN (wave 0) =================
    u32 aliveB = 0;
    int dirtyCnt = 0;
    bool consA = false;
    int resCode = 0, resIdx = 0;
    float dR0 = 0.f, dR1 = 0.f, dR2 = 0.f, dR3 = 0.f, dRa = 0.f;
    float dS0 = 0.f, dS1 = 0.f, dS2 = 0.f, dS3 = 0.f, dSs = 0.f;
    int dRank = INF, dGi = 0, dCnt = 0;
    float rm0 = 0.f, rm1 = 0.f, rm2 = 0.f, rm3 = 0.f, rma = 0.f;

    auto resolve = [&](int r, float bx0, float bx1, float bx2, float bx3,
                       float sc, float a1, u32 rowByte, u64 balC) {
        const u32 mC = rowByte & aliveB;
        int rank_c = INF;
        if (balC) {
            const int wl = (int)__builtin_ctzll(balC);
            const u32 byte = (u32)__builtin_amdgcn_readlane((int)mC, wl);
            rank_c = wl * 8 + (int)__builtin_ctz(byte);
        }
        // speculative clean-partner load (vectorized, overlaps dirty-rank work)
        const int rcs = (rank_c == INF) ? 0 : rank_c;
        const float4 cbv = *(const float4*)&s_det[rcs][0];
        const float4 cbe = *(const float4*)&s_det[rcs][4];
        const float cb0 = cbv.x, cb1 = cbv.y, cb2 = cbv.z, cb3 = cbv.w;
        const float csc = cbe.x;
        const int cgi = __float_as_int(cbe.z);

        int rank_d = INF, di = -1;
        if (dirtyCnt > 0) {
            const int DN = (dirtyCnt < 64) ? dirtyCnt : 64;
            const bool p = (lane < DN) &&
                iou_pred(bx0, bx1, bx2, bx3, a1, dR0, dR1, dR2, dR3, dRa);
            const int myrk = p ? dRank : INF;
            u64 mk = __ballot(p);
            while (mk) {
                const int l = (int)__builtin_ctzll(mk);
                mk &= mk - 1;
                const int rk = __builtin_amdgcn_readlane(myrk, l);
                if (rk < rank_d) { rank_d = rk; di = l; }
            }
            const int DH2 = (dirtyCnt < 128) ? dirtyCnt : 128;
            for (int dd = 64; dd < DH2; ++dd) {
                const float* dv = s_dov[dd];
                if (iou_pred(bx0, bx1, bx2, bx3, a1, dv[0], dv[1], dv[2], dv[3], dv[4])) {
                    const int rk = ((const int*)dv)[10];
                    if (rk < rank_d) { rank_d = rk; di = dd; }
                }
            }
        }
        if (rank_c == INF && rank_d == INF) {
            aliveB |= ((r >> 3) == lane) ? (1u << (r & 7)) : 0u;
            resCode = 0;
        } else if (rank_c < rank_d) {
            const int rc = rank_c;
            aliveB &= ~(((rc >> 3) == lane) ? (1u << (rc & 7)) : 0u);
            const float ns0 = (csc * cb0) + sc * bx0;
            const float ns1 = (csc * cb1) + sc * bx1;
            const float ns2 = (csc * cb2) + sc * bx2;
            const float ns3 = (csc * cb3) + sc * bx3;
            const float nss = csc + sc;
            const float nm0 = ns0 / nss, nm1 = ns1 / nss;
            const float nm2 = ns2 / nss, nm3 = ns3 / nss;
            const float nar = (nm2 - nm0) * (nm3 - nm1);
            const int D = dirtyCnt;
            if (D < 64) {
                if (lane == D) {
                    dR0 = nm0; dR1 = nm1; dR2 = nm2; dR3 = nm3; dRa = nar;
                    dS0 = ns0; dS1 = ns1; dS2 = ns2; dS3 = ns3; dSs = nss;
                    dRank = rc; dGi = cgi; dCnt = 2;
                }
            } else if (D < 128) {
                if (lane == 0) {
                    float* dv = s_dov[D];
                    dv[0] = nm0; dv[1] = nm1; dv[2] = nm2; dv[3] = nm3; dv[4] = nar;
                    dv[5] = ns0; dv[6] = ns1; dv[7] = ns2; dv[8] = ns3; dv[9] = nss;
                    ((int*)dv)[10] = rc; ((int*)dv)[11] = cgi; ((int*)dv)[12] = 2;
                }
            }
            dirtyCnt++;
            resCode = 1; resIdx = D;
            rm0 = nm0; rm1 = nm1; rm2 = nm2; rm3 = nm3; rma = nar;
        } else {
            float f0, f1, f2, f3, fs; int nct;
            if (di < 64) {
                f0 = rlF(dS0, di) + sc * bx0; f1 = rlF(dS1, di) + sc * bx1;
                f2 = rlF(dS2, di) + sc * bx2; f3 = rlF(dS3, di) + sc * bx3;
                fs = rlF(dSs, di) + sc;
                nct = __builtin_amdgcn_readlane(dCnt, di) + 1;
            } else {
                const float* dv = s_dov[di];
                f0 = dv[5] + sc * bx0; f1 = dv[6] + sc * bx1;
                f2 = dv[7] + sc * bx2; f3 = dv[8] + sc * bx3;
                fs = dv[9] + sc;
                nct = ((const int*)dv)[12] + 1;
            }
            const float nm0 = f0 / fs, nm1 = f1 / fs, nm2 = f2 / fs, nm3 = f3 / fs;
            const float nar = (nm2 - nm0) * (nm3 - nm1);
            if (di < 64) {
                if (lane == di) {
                    dR0 = nm0; dR1 = nm1; dR2 = nm2; dR3 = nm3; dRa = nar;
                    dS0 = f0; dS1 = f1; dS2 = f2; dS3 = f3; dSs = fs; dCnt = nct;
                }
            } else {
                if (lane == 0) {
                    float* dw = s_dov[di];
                    dw[0] = nm0; dw[1] = nm1; dw[2] = nm2; dw[3] = nm3; dw[4] = nar;
                    dw[5] = f0; dw[6] = f1; dw[7] = f2; dw[8] = f3; dw[9] = fs;
                    ((int*)dw)[12] = nct;
                }
            }
            rm0 = nm0; rm1 = nm1; rm2 = nm2; rm3 = nm3; rma = nar;
            resCode = 2; resIdx = di;
        }
    };

    // ---- batched scan: 64-det chunks ----
    unrollN<8>([&](auto k_) {
        constexpr int K = decltype(k_)::v;
        const int r0 = K * 64;
        if (r0 < myn) {
            const int cnt = (myn - r0 < 64) ? (myn - r0) : 64;
            const bool valid = lane < cnt;
            const u64 validM = (cnt == 64) ? ~0ull : (((u64)1 << cnt) - 1ull);
            u64 orv = 0ull;
            {
                const int rr = r0 + (valid ? lane : 0);
                const u64* rp = (const u64*)&s_mtx[(size_t)rr * 64];
                const u64* av = (const u64*)s_ab;
                unrollN<8>([&](auto w_) {
                    constexpr int W = decltype(w_)::v;
                    if (W < K)       orv |= rp[W] & av[W];
                    else if (W == K) orv |= rp[W];
                });
            }
            const u64 rowW = __ballot(valid && orv != 0ull);
            float4 db = make_float4(0.f, 0.f, 0.f, 0.f);
            float2 de = make_float2(1.f, 0.f);
            if (valid) {
                db = *(const float4*)&s_det[r0 + lane][0];
                de = *(const float2*)&s_det[r0 + lane][4];
            }
            u64 dmaskLo = 0ull, dmaskHi = 0ull;
            if (!consA) {
                const int DN = (dirtyCnt < 64) ? dirtyCnt : 64;
                for (int d = 0; d < DN; ++d) {
                    const float m0 = rlF(dR0, d), m1 = rlF(dR1, d);
                    const float m2 = rlF(dR2, d), m3 = rlF(dR3, d);
                    const float ma = rlF(dRa, d);
                    const bool pp = valid && iou_pred(db.x, db.y, db.z, db.w, de.y,
                                                     m0, m1, m2, m3, ma);
                    if (pp) dmaskLo |= 1ull << d;
                }
                const int DH = (dirtyCnt < 128) ? dirtyCnt : 128;
                for (int dd = 64; dd < DH; ++dd) {
                    const float* dv = s_dov[dd];
                    const bool pp = valid && iou_pred(db.x, db.y, db.z, db.w, de.y,
                                                     dv[0], dv[1], dv[2], dv[3], dv[4]);
                    if (pp) dmaskHi |= 1ull << (dd - 64);
                }
            }
            u64 danyb = __ballot((dmaskLo | dmaskHi) != 0ull);

            // prefetch row bytes for the first 8 candidate violations
            u32 prB[8]; int prP[8];
            {
                u64 t = consA ? validM : ((danyb | rowW) & validM);
                #pragma unroll
                for (int i = 0; i < 8; ++i) {
                    const int f = t ? (int)__builtin_ctzll(t) : 0;
                    prP[i] = t ? f : 64;
                    prB[i] = (u32)s_mtx[(size_t)(r0 + f) * 64 + lane];
                    t &= t - 1ull;
                }
            }

            int p = 0;
            while (p < cnt) {
                u64 vm = consA ? validM : ((danyb | rowW) & validM);
                vm &= ~(((u64)1 << p) - 1ull);
                const int F = vm ? (int)__builtin_ctzll(vm) : cnt;
                {   // commit creates [r0+p, r0+F)
                    const int lo = r0 + p, h2 = r0 + F;
                    int s = lo - 8 * lane; s = (s > 0) ? s : 0;
                    int e = h2 - 8 * lane; e = (e < 8) ? e : 8;
                    if (e > s) aliveB |= ((0xFFu >> (8 - (e - s))) << s);
                }
                s_ab[lane] = (u8)aliveB;
                if (F >= cnt) break;
                const int r = r0 + F;
                u32 rowByte = 0u; bool hit = false;
                #pragma unroll
                for (int i = 0; i < 8; ++i)
                    if (prP[i] == F) { rowByte = prB[i]; hit = true; }
                if (!hit) rowByte = (u32)s_mtx[(size_t)r * 64 + lane];
                const u64 balCq = __ballot((rowByte & aliveB) != 0u);
                const bool Fdirty = consA || (((danyb >> F) & 1ull) != 0ull);
                if (!Fdirty && balCq == 0ull) {
                    aliveB |= ((r >> 3) == lane) ? (1u << (r & 7)) : 0u;
                    s_ab[lane] = (u8)aliveB;
                } else {
                    const float bx0 = rlF(db.x, F), bx1 = rlF(db.y, F);
                    const float bx2 = rlF(db.z, F), bx3 = rlF(db.w, F);
                    const float sc = rlF(de.x, F), a1 = rlF(de.y, F);
                    resolve(r, bx0, bx1, bx2, bx3, sc, a1, rowByte, balCq);
                    s_ab[lane] = (u8)aliveB;
                    if (resCode != 0) {
                        const int idx = resIdx;
                        if (idx < 128) {
                            const bool pnew = valid && (lane > F) &&
                                iou_pred(db.x, db.y, db.z, db.w, de.y,
                                         rm0, rm1, rm2, rm3, rma);
                            const u64 nb = __ballot(pnew);
                            const u64 bit = (nb >> lane) & 1ull;
                            if (idx < 64)
                                dmaskLo = (dmaskLo & ~(1ull << idx)) | (bit << idx);
                            else
                                dmaskHi = (dmaskHi & ~(1ull << (idx - 64))) | (bit << (idx - 64));
                            danyb = __ballot((dmaskLo | dmaskHi) != 0ull);
                        } else {
                            consA = true;
                        }
                    }
                }
                p = F + 1;
            }
        }
    });

    // ---- emit compacted records + sort keys + global histogram ----
    int wo = 0;
    for (int Kw = 0; Kw < 8; ++Kw) {
        u64 am = 0ull;
        #pragma unroll
        for (int bb = 0; bb < 8; ++bb)
            am |= (u64)(u32)(u8)__builtin_amdgcn_readlane((int)aliveB, Kw * 8 + bb) << (8 * bb);
        const int j = Kw * 64 + lane;
        const bool pred = (am >> lane) & 1ull;
        if (pred) {
            const int pos = wo + (int)__popcll(am & (((u64)1 << lane) - 1));
            const float b0 = s_det[j][0], b1 = s_det[j][1];
            const float b2 = s_det[j][2], b3 = s_det[j][3];
            const float sc = s_det[j][4];
            const int g = ((const int*)s_det[j])[6];
            const int id = cls * CAP + pos;
            float* rec = recs + (size_t)id * 8;
            rec[0] = (sc * b0) / sc; rec[1] = (sc * b1) / sc;
            rec[2] = (sc * b2) / sc; rec[3] = (sc * b3) / sc;
            rec[4] = sc;
            ((int*)rec)[5] = g;
            const u64 skey = mk_key(sc, g, id);
            keysg[id] = skey;
            atomicAdd(&histg[(u32)(skey >> 52)], 1u);
        }
        wo += (int)__popcll(am);
    }
    const int demit = (dirtyCnt < 128) ? dirtyCnt : 128;
    {
        const int dreg = (demit < 64) ? demit : 64;
        if (lane < dreg) {
            const int id = cls * CAP + wo + lane;
            float* rec = recs + (size_t)id * 8;
            const float scd = dSs / (float)dCnt;   // exact IEEE div
            rec[0] = dR0; rec[1] = dR1; rec[2] = dR2; rec[3] = dR3;
            rec[4] = scd;
            ((int*)rec)[5] = dGi;
            const u64 skey = mk_key(scd, dGi, id);
            keysg[id] = skey;
            atomicAdd(&histg[(u32)(skey >> 52)], 1u);
        }
        for (int d = 64 + lane; d < demit; d += 64) {
            const float* dv = s_dov[d];
            const int id = cls * CAP + wo + d;
            float* rec = recs + (size_t)id * 8;
            const float scd = dv[9] / (float)(((const int*)dv)[12]);
            const int g = ((const int*)dv)[11];
            rec[0] = dv[0]; rec[1] = dv[1]; rec[2] = dv[2]; rec[3] = dv[3];
            rec[4] = scd;
            ((int*)rec)[5] = g;
            const u64 skey = mk_key(scd, g, id);
            keysg[id] = skey;
            atomicAdd(&histg[(u32)(skey >> 52)], 1u);
        }
    }
    if (lane == 0) cnts[cls] = wo + demit;
}

// ================= K3: SORT (8 blocks, parallel rank) =========================
// Each block redundantly computes threshold + deterministic compaction (no
// atomics -> identical cand[] everywhere); block g ranks candidates
// [g*64, g*64+64) and writes its out rows directly. Block 0 zero-fills tail.
__global__ __launch_bounds__(512, 1) void wbf_sort(const u64* __restrict__ keysg,
                                                   const u32* __restrict__ histg,
                                                   const float* __restrict__ recs,
                                                   const int* __restrict__ cnts,
                                                   float* __restrict__ out) {
    __shared__ __align__(16) char s_buf[28864];
    u64* keysL   = (u64*)s_buf;             // 20480 (fallback path only)
    u64* cand    = (u64*)(s_buf + 20480);   // 4096
    u32* partial = (u32*)(s_buf + 24576);   // 2048: 8 waves x 64 lanes
    u32* part    = (u32*)(s_buf + 26624);   // 32: wave prefix totals
    int* wcnt    = (int*)(s_buf + 26656);   // 32: compaction wave counts
    int* scal    = (int*)(s_buf + 26688);

    const int tid  = threadIdx.x;
    const int lane = tid & 63;
    const int wave = tid >> 6;
    const int g    = blockIdx.x;

    if (tid == 0) { scal[0] = 0; scal[1] = 0; }

    int n = 0;
    #pragma unroll
    for (int w = 0; w < NCLS; ++w) n += cnts[w];
    const int target = (POST < n) ? POST : n;

    // prefix over 4096 bins: 8 bins/thread + shfl scan (1 barrier)
    u32 p = 0;
    #pragma unroll
    for (int k = 0; k < 8; ++k) p += histg[tid * 8 + k];
    u32 v = p;
    #pragma unroll
    for (int o2 = 1; o2 < 64; o2 <<= 1) {
        const u32 t = (u32)__shfl_up((int)v, o2);
        if (lane >= o2) v += t;
    }
    if (lane == 63) part[wave] = v;
    __syncthreads();
    u32 base = 0;
    #pragma unroll
    for (int w = 0; w < 8; ++w) base += (w < wave) ? part[w] : 0u;
    const u32 I = base + v;
    const u32 E = I - p;
    if ((int)E < target && (int)I >= target) { scal[0] = tid; scal[1] = (int)E; }
    __syncthreads();
    const int T = scal[0];
    int cum = scal[1];
    int B = T * 8 + 7;
    for (int bb = T * 8; bb < T * 8 + 8; ++bb) {
        const int h = (int)histg[bb];
        if (cum + h >= target) { B = bb; break; }
        cum += h;
    }
    const int candCount = cum + (int)histg[B];

    if (candCount <= 512) {
        // deterministic compaction over 2560 fixed slots (pads self-exclude):
        // ballot + wave-count prefix, no atomics -> cand[] identical per block
        int running = 0;
        #pragma unroll
        for (int c5 = 0; c5 < 5; ++c5) {
            const u64 kk = keysg[c5 * 512 + tid];
            const bool pred = ((u32)(kk >> 52) <= (u32)B);
            const u64 m = __ballot(pred);
            if (lane == 0) wcnt[wave] = (int)__popcll(m);
            __syncthreads();
            int wb = running;
            #pragma unroll
            for (int w = 0; w < 8; ++w) {
                wb += (w < wave) ? wcnt[w] : 0;
                running += wcnt[w];
            }
            if (pred)
                cand[wb + (int)__popcll(m & (((u64)1 << lane) - 1ull))] = kk;
            __syncthreads();
        }
        // unique pads, strictly greater than every real key
        if (tid >= candCount) cand[tid] = (~0ull << 16) | (u64)(0xF000u + tid);
        __syncthreads();

        // parallel rank: wave w counts candidate (g*64+lane) against chunk w
        const u64 kc = cand[g * 64 + lane];
        int pc = 0;
        #pragma unroll 8
        for (int j = 0; j < 64; ++j) {
            const u64 kj = cand[wave * 64 + j];
            pc += (int)(kj < kc);   // keys unique: strict <
        }
        partial[wave * 64 + lane] = (u32)pc;
        __syncthreads();
        if (wave == 0) {
            int rk = 0;
            #pragma unroll
            for (int w = 0; w < 8; ++w) rk += (int)partial[w * 64 + lane];
            if (rk < target) {   // pads rank >= candCount >= target: excluded
                const u64 key = ~kc;
                const int id = (int)(key & 0xFFFFull);
                const float* rec = recs + (size_t)id * 8;
                float* o = out + rk * 6;
                o[0] = rec[0]; o[1] = rec[1]; o[2] = rec[2]; o[3] = rec[3];
                o[4] = __uint_as_float((unsigned)(key >> 32));
                o[5] = (float)(id >> 9);
            }
        }
        if (g == 0 && tid >= target && tid < POST) {
            float* o = out + tid * 6;
            o[0] = 0.f; o[1] = 0.f; o[2] = 0.f; o[3] = 0.f; o[4] = 0.f; o[5] = 0.f;
        }
    } else {
        // fallback (~never): block 0 full-ranks all 2560 slots, 5 per thread
        if (g != 0) return;
        for (int i = tid; i < NCLS * CAP; i += 512) keysL[i] = keysg[i];
        __syncthreads();
        u64 myk5[5]; int rk5[5];
        #pragma unroll
        for (int s = 0; s < 5; ++s) { myk5[s] = keysL[s * 512 + tid]; rk5[s] = 0; }
        for (int j = 0; j < NCLS * CAP; ++j) {
            const u64 kj = keysL[j];
            #pragma unroll
            for (int s = 0; s < 5; ++s)
                rk5[s] += (int)((kj < myk5[s]) || (kj == myk5[s] && j < s * 512 + tid));
        }
        #pragma unroll
        for (int s = 0; s < 5; ++s) {
            const int rk = rk5[s];
            if (rk < target) {
                const u64 key = ~myk5[s];
                const int id = (int)(key & 0xFFFFull);
                const float* rec = recs + (size_t)id * 8;
                float* o = out + rk * 6;
                o[0] = rec[0]; o[1] = rec[1]; o[2] = rec[2]; o[3] = rec[3];
                o[4] = __uint_as_float((unsigned)(key >> 32));
                o[5] = (float)(id >> 9);
            }
        }
        if (tid >= target && tid < POST) {
            float* o = out + tid * 6;
            o[0] = 0.f; o[1] = 0.f; o[2] = 0.f; o[3] = 0.f; o[4] = 0.f; o[5] = 0.f;
        }
    }
}

extern "C" void kernel_launch(void* const* d_in, const int* in_sizes, int n_in,
                              void* d_out, int out_size, void* d_ws, size_t ws_size,
                              hipStream_t stream) {
    const float* x = (const float*)d_in[0];
    float* out = (float*)d_out;
    // ws layout: M 160K | dets 80K | recs 80K | cnts/nlist 256B | keys 20K | hist 16K
    u64*   M     = (u64*)d_ws;
    float* dets  = (float*)((char*)d_ws + 163840);
    float* recs  = (float*)((char*)d_ws + 245760);
    int*   cnts  = (int*)((char*)d_ws + 327680);
    int*   nlist = cnts + 16;
    u64*   keysg = (u64*)((char*)d_ws + 327936);
    u32*   histg = (u32*)((char*)d_ws + 348416);
    wbf_matrix<<<NCLS * 16, 512, 0, stream>>>(x, M, dets, nlist, keysg, histg);
    wbf_scan<<<NCLS, 512, 0, stream>>>(M, dets, nlist, recs, cnts, keysg, histg);
    wbf_sort<<<SORTG, 512, 0, stream>>>(keysg, histg, recs, cnts, out);
}